// Round 4
// baseline (394.789 us; speedup 1.0000x reference)
//
#include <hip/hip_runtime.h>
#include <hip/hip_bf16.h>
#include <math.h>

#define N_NODES 100000
#define C 256
#define NB 64
#define H1D 128
#define NG 128
#define GS 257            // gsums row stride: 256 channels + 1 count
#define BN_EPS 1e-5f

#define BLKN 64
#define NBLK1 ((N_NODES + BLKN - 1) / BLKN)   // 1563

// ws layout (float offsets)
#define OFF_GSUMS 0
#define OFF_BNSUM (NG * GS)              // 32896
#define OFF_BNSQ  (OFF_BNSUM + 256)      // 33152
#define ZERO_FLOATS (OFF_BNSQ + 256)     // 33408 floats zeroed each launch
#define OFF_HMEAN ZERO_FLOATS            // 33408
#define OFF_WT1   (OFF_HMEAN + NG * C)   // 66176 ; 128x264 bf16 = 16896 floats
#define OFF_WT2   (OFF_WT1 + 16896)      // 83072 ; 64x136 bf16 = 4352 floats
#define OFF_CSN   (OFF_WT2 + 4352)       // 87424 ; N*128 bf16 = 6.4M floats

#define WT1_LD 264   // bf16 stride (256 + 8 pad, 16B-aligned rows)
#define WT2_LD 136

typedef __attribute__((ext_vector_type(8))) short bf16x8;
typedef __attribute__((ext_vector_type(4))) float f32x4;

struct __align__(8) bf4 { __hip_bfloat16 x, y, z, w; };

__device__ __forceinline__ float bf2f(__hip_bfloat16 h) { return __bfloat162float(h); }

// ---------------------------------------------------------------------------
// K0: transpose+convert weights to bf16 [out_ch][in_ch] layout for MFMA B-frags
// ---------------------------------------------------------------------------
__global__ __launch_bounds__(256)
void k0_prep(const float* __restrict__ W1, const float* __restrict__ W2,
             __hip_bfloat16* __restrict__ Wt1, __hip_bfloat16* __restrict__ Wt2)
{
    const int t0 = threadIdx.x + blockIdx.x * 256;
    const int stride = gridDim.x * 256;
    for (int i = t0; i < 128 * 256; i += stride) {
        int n = i >> 8, k = i & 255;
        Wt1[n * WT1_LD + k] = __float2bfloat16(W1[k * 128 + n]);
    }
    for (int i = t0; i < 64 * 128; i += stride) {
        int n = i >> 7, k = i & 127;
        Wt2[n * WT2_LD + k] = __float2bfloat16(W2[k * 64 + n]);
    }
}

// ---------------------------------------------------------------------------
// K1: 64-node tile. MFMA GEMM1 (bf16) -> GELU -> MFMA GEMM2 -> tanh -> sincos;
//     write interleaved cos/sin (bf16) to global; rotate fibers; pooled sums.
// ---------------------------------------------------------------------------
__global__ __launch_bounds__(256, 3)
void k1_angles_rot_pool(const float* __restrict__ x,
                        const int* __restrict__ batch,
                        const __hip_bfloat16* __restrict__ Wt1g,
                        const float* __restrict__ b1,
                        const __hip_bfloat16* __restrict__ Wt2g,
                        const float* __restrict__ b2,
                        float* __restrict__ gsums,
                        __hip_bfloat16* __restrict__ csng)
{
    __shared__ __hip_bfloat16 xs[BLKN][264];    // 33792 B
    __shared__ char sm_u[BLKN * WT2_LD * 2];    // 17408 B: h1s, later csn (aliased)
    __shared__ int gsh[BLKN];                   // 256 B   -> total 51456 B, 3 blk/CU
    auto h1s = (__hip_bfloat16 (*)[WT2_LD])sm_u;   // stride 136
    auto csn = (__hip_bfloat16 (*)[132])sm_u;      // stride 132: [2c]=cos,[2c+1]=sin

    const int t = threadIdx.x;
    const int w = t >> 6;                 // wave 0..3
    const int l = t & 63;
    const int lo = l & 15, quad = l >> 4;
    const int n0 = blockIdx.x * BLKN;
    const int nrem = min(BLKN, N_NODES - n0);

    // ---- Phase A: x fp32 -> bf16 LDS tile (zero-fill tail rows); batch tile ----
    #pragma unroll
    for (int m = 0; m < 16; ++m) {
        int idx = t + m * 256;
        int r = idx >> 6, c4 = (idx & 63) * 4;
        float4 v;
        if (n0 + r < N_NODES) v = *(const float4*)(x + (size_t)(n0 + r) * C + c4);
        else { v.x = v.y = v.z = v.w = 0.f; }
        bf4 pk;
        pk.x = __float2bfloat16(v.x); pk.y = __float2bfloat16(v.y);
        pk.z = __float2bfloat16(v.z); pk.w = __float2bfloat16(v.w);
        *(bf4*)&xs[r][c4] = pk;                 // 8B LDS store, contiguous per wave
    }
    if (t < BLKN) gsh[t] = batch[min(n0 + t, N_NODES - 1)];

    // ---- Preload B-fragments (GEMM1: wave owns n-tiles 2w,2w+1; GEMM2: all) ----
    bf16x8 bfr[2][8];
    #pragma unroll
    for (int nt = 0; nt < 2; ++nt) {
        const short* base = (const short*)Wt1g + (w * 32 + nt * 16 + lo) * WT1_LD + quad * 8;
        #pragma unroll
        for (int k = 0; k < 8; ++k) bfr[nt][k] = *(const bf16x8*)(base + k * 32);
    }
    bf16x8 b2f[4][4];
    #pragma unroll
    for (int nt = 0; nt < 4; ++nt) {
        const short* base = (const short*)Wt2g + (nt * 16 + lo) * WT2_LD + quad * 8;
        #pragma unroll
        for (int k = 0; k < 4; ++k) b2f[nt][k] = *(const bf16x8*)(base + k * 32);
    }
    __syncthreads();

    // ---- GEMM1: h1 = x[64,256] @ W1[256,128]; wave: 4 Mtiles x 2 Ntiles ----
    f32x4 acc1[4][2];
    #pragma unroll
    for (int mt = 0; mt < 4; ++mt) { acc1[mt][0] = (f32x4)0.f; acc1[mt][1] = (f32x4)0.f; }
    #pragma unroll
    for (int mt = 0; mt < 4; ++mt) {
        #pragma unroll
        for (int k = 0; k < 8; ++k) {
            bf16x8 afr = *(const bf16x8*)&xs[mt * 16 + lo][k * 32 + quad * 8];
            acc1[mt][0] = __builtin_amdgcn_mfma_f32_16x16x32_bf16(afr, bfr[0][k], acc1[mt][0], 0, 0, 0);
            acc1[mt][1] = __builtin_amdgcn_mfma_f32_16x16x32_bf16(afr, bfr[1][k], acc1[mt][1], 0, 0, 0);
        }
    }
    // bias + exact GELU -> h1s (row = mt*16+quad*4+r, col = w*32+nt*16+lo)
    #pragma unroll
    for (int nt = 0; nt < 2; ++nt) {
        const float bb = b1[w * 32 + nt * 16 + lo];
        #pragma unroll
        for (int mt = 0; mt < 4; ++mt) {
            #pragma unroll
            for (int r = 0; r < 4; ++r) {
                float v = acc1[mt][nt][r] + bb;
                v = 0.5f * v * (1.0f + erff(v * 0.70710678118654752f));
                h1s[mt * 16 + quad * 4 + r][w * 32 + nt * 16 + lo] = __float2bfloat16(v);
            }
        }
    }
    __syncthreads();

    // ---- GEMM2: ang = h1[64,128] @ W2[128,64]; wave owns Mtile w, 4 Ntiles ----
    f32x4 acc2[4];
    #pragma unroll
    for (int nt = 0; nt < 4; ++nt) acc2[nt] = (f32x4)0.f;
    #pragma unroll
    for (int k = 0; k < 4; ++k) {
        bf16x8 afr = *(const bf16x8*)&h1s[w * 16 + lo][k * 32 + quad * 8];
        #pragma unroll
        for (int nt = 0; nt < 4; ++nt)
            acc2[nt] = __builtin_amdgcn_mfma_f32_16x16x32_bf16(afr, b2f[nt][k], acc2[nt], 0, 0, 0);
    }
    __syncthreads();   // h1s reads done; csn may now overwrite the same LDS

    // tanh -> sincos -> interleaved csn (one 4B store per value pair)
    #pragma unroll
    for (int nt = 0; nt < 4; ++nt) {
        const float bb = b2[nt * 16 + lo];
        #pragma unroll
        for (int r = 0; r < 4; ++r) {
            float a = tanhf(acc2[nt][r] + bb);
            float sv, cv;
            sincosf(a, &sv, &cv);
            union { unsigned int u; __hip_bfloat16 h[2]; } p;
            p.h[0] = __float2bfloat16(cv);
            p.h[1] = __float2bfloat16(sv);
            *(unsigned int*)&csn[w * 16 + quad * 4 + r][2 * (nt * 16 + lo)] = p.u;
        }
    }
    __syncthreads();

    // ---- coalesced global write of interleaved cos/sin ----
    #pragma unroll
    for (int m = 0; m < 16; ++m) {
        int idx = t + m * 256;            // 0..4095 : 64 rows x 64 dwords
        int row = idx >> 6;
        int d = (idx & 63) * 2;
        if (n0 + row < N_NODES)
            *(unsigned int*)(csng + (size_t)(n0 + row) * 128 + d) = *(const unsigned int*)&csn[row][d];
    }

    // ---- Phase D: rotate + segment-reduce pooled sums (thread = channel) ----
    {
        const int b = t >> 2;
        const int idx2 = t & 3;
        const int i2 = idx2 >> 1;
        const int f = idx2 & 1;
        float racc = 0.f, rcnt = 0.f;
        int gprev = gsh[0];
        #pragma unroll 16
        for (int r = 0; r < BLKN; ++r) {
            const int g = gsh[r];
            if (g != gprev) {
                atomicAdd(&gsums[gprev * GS + t], racc);
                if (t == 0) atomicAdd(&gsums[gprev * GS + 256], rcnt);
                racc = 0.f; rcnt = 0.f; gprev = g;
            }
            bf4 xq = *(const bf4*)&xs[r][4 * b];             // one ds_read_b64
            union { unsigned int u; __hip_bfloat16 h[2]; } cs;
            cs.u = *(const unsigned int*)&csn[r][2 * b];     // one ds_read_b32
            const float x0 = f ? bf2f(xq.y) : bf2f(xq.x);
            const float x1 = f ? bf2f(xq.w) : bf2f(xq.z);
            const float cb = bf2f(cs.h[0]);
            const float sb = bf2f(cs.h[1]);
            racc += (i2 == 0) ? (cb * x0 - sb * x1) : (sb * x0 + cb * x1);
            rcnt += (r < nrem) ? 1.f : 0.f;
        }
        atomicAdd(&gsums[gprev * GS + t], racc);
        if (t == 0) atomicAdd(&gsums[gprev * GS + 256], rcnt);
    }
}

// ---------------------------------------------------------------------------
// K2: hmean[g] = (gsum[g] @ lin_w) / cnt + lin_b   (0 if cnt == 0)
// ---------------------------------------------------------------------------
__global__ __launch_bounds__(256)
void k2_hmean(const float* __restrict__ gsums, const float* __restrict__ lin_w,
              const float* __restrict__ lin_b, float* __restrict__ hmean)
{
    __shared__ float gs[C];
    __shared__ float cnt_sh;
    const int g = blockIdx.x;
    const int t = threadIdx.x;
    gs[t] = gsums[g * GS + t];
    if (t == 0) cnt_sh = gsums[g * GS + 256];
    __syncthreads();
    float a0 = 0.f, a1 = 0.f, a2 = 0.f, a3 = 0.f;
    #pragma unroll 4
    for (int k = 0; k < C; k += 4) {
        a0 += gs[k + 0] * lin_w[(size_t)(k + 0) * C + t];
        a1 += gs[k + 1] * lin_w[(size_t)(k + 1) * C + t];
        a2 += gs[k + 2] * lin_w[(size_t)(k + 2) * C + t];
        a3 += gs[k + 3] * lin_w[(size_t)(k + 3) * C + t];
    }
    const float cnt = cnt_sh;
    hmean[g * C + t] = (cnt > 0.f) ? ((a0 + a1 + a2 + a3) / cnt + lin_b[t]) : 0.f;
}

// ---------------------------------------------------------------------------
// K3: out = x + R^T hmean[batch[n]] (interleaved cos/sin bf16); BN partials.
// ---------------------------------------------------------------------------
__global__ __launch_bounds__(256, 4)
void k3_inverse_resid(const float* __restrict__ x,
                      const int* __restrict__ batch,
                      const __hip_bfloat16* __restrict__ csng,
                      const float* __restrict__ hmean,
                      float* __restrict__ out,
                      float* __restrict__ bnsum, float* __restrict__ bnsq)
{
    __shared__ float rs[4][C];
    __shared__ float rq[4][C];
    const int t = threadIdx.x;
    const int s = t >> 6;
    const int cg = t & 63;
    float bs0 = 0.f, bs1 = 0.f, bs2 = 0.f, bs3 = 0.f;
    float bq0 = 0.f, bq1 = 0.f, bq2 = 0.f, bq3 = 0.f;

    for (int base = blockIdx.x * 4; base < N_NODES; base += gridDim.x * 4) {
        const int n = base + s;
        if (n < N_NODES) {
            const int g = batch[n];
            const float4 hm = *(const float4*)(hmean + (size_t)g * C + cg * 4);
            union { unsigned int u; __hip_bfloat16 h[2]; } cs;
            cs.u = *(const unsigned int*)(csng + (size_t)n * 128 + cg * 2);
            const float cv = bf2f(cs.h[0]);
            const float sv = bf2f(cs.h[1]);
            const float4 xv = *(const float4*)(x + (size_t)n * C + cg * 4);
            float4 o;
            o.x = xv.x + cv * hm.x + sv * hm.z;
            o.y = xv.y + cv * hm.y + sv * hm.w;
            o.z = xv.z - sv * hm.x + cv * hm.z;
            o.w = xv.w - sv * hm.y + cv * hm.w;
            *(float4*)(out + (size_t)n * C + cg * 4) = o;
            bs0 += o.x; bs1 += o.y; bs2 += o.z; bs3 += o.w;
            bq0 += o.x * o.x; bq1 += o.y * o.y; bq2 += o.z * o.z; bq3 += o.w * o.w;
        }
    }
    rs[s][cg * 4 + 0] = bs0; rs[s][cg * 4 + 1] = bs1;
    rs[s][cg * 4 + 2] = bs2; rs[s][cg * 4 + 3] = bs3;
    rq[s][cg * 4 + 0] = bq0; rq[s][cg * 4 + 1] = bq1;
    rq[s][cg * 4 + 2] = bq2; rq[s][cg * 4 + 3] = bq3;
    __syncthreads();
    atomicAdd(&bnsum[t], rs[0][t] + rs[1][t] + rs[2][t] + rs[3][t]);
    atomicAdd(&bnsq[t],  rq[0][t] + rq[1][t] + rq[2][t] + rq[3][t]);
}

// ---------------------------------------------------------------------------
// K4: BatchNorm finalize, in place over d_out.
// ---------------------------------------------------------------------------
__global__ __launch_bounds__(256)
void k4_bn(float* __restrict__ out, const float* __restrict__ bnsum,
           const float* __restrict__ bnsq, const float* __restrict__ gamma,
           const float* __restrict__ beta)
{
    __shared__ float mul_s[C], add_s[C];
    const int t = threadIdx.x;
    {
        const float inv_n = 1.0f / (float)N_NODES;
        const float mu = bnsum[t] * inv_n;
        const float var = bnsq[t] * inv_n - mu * mu;
        const float inv = rsqrtf(var + BN_EPS);
        const float m = gamma[t] * inv;
        mul_s[t] = m;
        add_s[t] = beta[t] - mu * m;
    }
    __syncthreads();
    float4* o4 = (float4*)out;
    const size_t total = (size_t)N_NODES * C / 4;
    for (size_t i = (size_t)blockIdx.x * 256 + t; i < total;
         i += (size_t)gridDim.x * 256) {
        float4 v = o4[i];
        const int c0 = ((int)(i & 63)) * 4;
        v.x = v.x * mul_s[c0 + 0] + add_s[c0 + 0];
        v.y = v.y * mul_s[c0 + 1] + add_s[c0 + 1];
        v.z = v.z * mul_s[c0 + 2] + add_s[c0 + 2];
        v.w = v.w * mul_s[c0 + 3] + add_s[c0 + 3];
        o4[i] = v;
    }
}

// ---------------------------------------------------------------------------
extern "C" void kernel_launch(void* const* d_in, const int* in_sizes, int n_in,
                              void* d_out, int out_size, void* d_ws, size_t ws_size,
                              hipStream_t stream)
{
    const float* x      = (const float*)d_in[0];
    // d_in[1] = edge_index (unused, num_gnn == 0)
    const int* batch    = (const int*)d_in[2];
    const float* W1     = (const float*)d_in[3];
    const float* b1     = (const float*)d_in[4];
    const float* W2     = (const float*)d_in[5];
    const float* b2     = (const float*)d_in[6];
    const float* lin_w  = (const float*)d_in[7];
    const float* lin_b  = (const float*)d_in[8];
    const float* gamma  = (const float*)d_in[9];
    const float* beta   = (const float*)d_in[10];

    float* ws    = (float*)d_ws;
    float* gsums = ws + OFF_GSUMS;
    float* bnsum = ws + OFF_BNSUM;
    float* bnsq  = ws + OFF_BNSQ;
    float* hmean = ws + OFF_HMEAN;
    __hip_bfloat16* Wt1  = (__hip_bfloat16*)(ws + OFF_WT1);
    __hip_bfloat16* Wt2  = (__hip_bfloat16*)(ws + OFF_WT2);
    __hip_bfloat16* csng = (__hip_bfloat16*)(ws + OFF_CSN);
    float* out   = (float*)d_out;

    hipMemsetAsync(gsums, 0, ZERO_FLOATS * sizeof(float), stream);

    k0_prep<<<32, 256, 0, stream>>>(W1, W2, Wt1, Wt2);
    k1_angles_rot_pool<<<NBLK1, 256, 0, stream>>>(x, batch, Wt1, b1, Wt2, b2,
                                                  gsums, csng);
    k2_hmean<<<NG, 256, 0, stream>>>(gsums, lin_w, lin_b, hmean);
    k3_inverse_resid<<<1024, 256, 0, stream>>>(x, batch, csng, hmean, out,
                                               bnsum, bnsq);
    k4_bn<<<2048, 256, 0, stream>>>(out, bnsum, bnsq, gamma, beta);
}

// Round 5
// 346.865 us; speedup vs baseline: 1.1382x; 1.1382x over previous
//
#include <hip/hip_runtime.h>
#include <hip/hip_bf16.h>
#include <math.h>

#define N_NODES 100000
#define C 256
#define NB 64
#define H1D 128
#define NG 128
#define GS 257            // gsums row stride: 256 channels + 1 count
#define BN_EPS 1e-5f

#define BLKN 64
#define NBLK1 ((N_NODES + BLKN - 1) / BLKN)   // 1563

// ws layout (float offsets)
#define OFF_GSUMS 0
#define OFF_BNSUM (NG * GS)              // 32896
#define OFF_BNSQ  (OFF_BNSUM + 256)      // 33152
#define ZERO_FLOATS (OFF_BNSQ + 256)     // 33408 floats zeroed each launch
#define OFF_HMEAN ZERO_FLOATS            // 33408
#define OFF_WT1   (OFF_HMEAN + NG * C)   // 66176 ; 128x264 bf16 = 16896 floats
#define OFF_WT2   (OFF_WT1 + 16896)      // 83072 ; 64x136 bf16 = 4352 floats
#define OFF_CSN   (OFF_WT2 + 4352)       // 87424 ; N*128 bf16 = 6.4M floats

#define WT1_LD 264   // bf16 stride of Wt1 in global (16B-aligned rows)
#define WT2_LD 136
#define XS_LD  272   // bf16 stride of xs in LDS: row shift = 8 banks -> 4-way max

typedef __attribute__((ext_vector_type(8))) short bf16x8;
typedef __attribute__((ext_vector_type(4))) float f32x4;

struct __align__(8) bf4 { __hip_bfloat16 x, y, z, w; };

__device__ __forceinline__ float bf2f(__hip_bfloat16 h) { return __bfloat162float(h); }

// ---------------------------------------------------------------------------
// K0: transpose+convert weights to bf16 [out_ch][in_ch] layout for MFMA B-frags
// ---------------------------------------------------------------------------
__global__ __launch_bounds__(256)
void k0_prep(const float* __restrict__ W1, const float* __restrict__ W2,
             __hip_bfloat16* __restrict__ Wt1, __hip_bfloat16* __restrict__ Wt2)
{
    const int t0 = threadIdx.x + blockIdx.x * 256;
    const int stride = gridDim.x * 256;
    for (int i = t0; i < 128 * 256; i += stride) {
        int n = i >> 8, k = i & 255;
        Wt1[n * WT1_LD + k] = __float2bfloat16(W1[k * 128 + n]);
    }
    for (int i = t0; i < 64 * 128; i += stride) {
        int n = i >> 7, k = i & 127;
        Wt2[n * WT2_LD + k] = __float2bfloat16(W2[k * 64 + n]);
    }
}

// ---------------------------------------------------------------------------
// K1: 64-node tile. MFMA GEMM1 (bf16) -> GELU -> MFMA GEMM2 -> tanh -> sincos;
//     write interleaved cos/sin (bf16) to global; rotate fibers; pooled sums.
//     B-fragments loaded per-k inside the loops (low register pressure:
//     preloading all 32 frags = 128 VGPRs spilled to scratch in R4).
// ---------------------------------------------------------------------------
__global__ __launch_bounds__(256, 3)
void k1_angles_rot_pool(const float* __restrict__ x,
                        const int* __restrict__ batch,
                        const __hip_bfloat16* __restrict__ Wt1g,
                        const float* __restrict__ b1,
                        const __hip_bfloat16* __restrict__ Wt2g,
                        const float* __restrict__ b2,
                        float* __restrict__ gsums,
                        __hip_bfloat16* __restrict__ csng)
{
    __shared__ __hip_bfloat16 xs[BLKN][XS_LD];  // 34816 B
    __shared__ char sm_u[BLKN * WT2_LD * 2];    // 17408 B: h1s, later csn (aliased)
    __shared__ int gsh[BLKN];                   // 256 B   -> total 52480 B, 3 blk/CU
    auto h1s = (__hip_bfloat16 (*)[WT2_LD])sm_u;   // stride 136
    auto csn = (__hip_bfloat16 (*)[132])sm_u;      // stride 132: [2c]=cos,[2c+1]=sin

    const int t = threadIdx.x;
    const int w = t >> 6;                 // wave 0..3
    const int l = t & 63;
    const int lo = l & 15, quad = l >> 4;
    const int n0 = blockIdx.x * BLKN;
    const int nrem = min(BLKN, N_NODES - n0);

    // ---- Phase A: x fp32 -> bf16 LDS tile (zero-fill tail rows); batch tile ----
    #pragma unroll
    for (int m = 0; m < 16; ++m) {
        int idx = t + m * 256;
        int r = idx >> 6, c4 = (idx & 63) * 4;
        float4 v;
        if (n0 + r < N_NODES) v = *(const float4*)(x + (size_t)(n0 + r) * C + c4);
        else { v.x = v.y = v.z = v.w = 0.f; }
        bf4 pk;
        pk.x = __float2bfloat16(v.x); pk.y = __float2bfloat16(v.y);
        pk.z = __float2bfloat16(v.z); pk.w = __float2bfloat16(v.w);
        *(bf4*)&xs[r][c4] = pk;
    }
    if (t < BLKN) gsh[t] = batch[min(n0 + t, N_NODES - 1)];
    __syncthreads();

    // ---- GEMM1: h1 = x[64,256] @ W1[256,128]; wave: 4 Mtiles x 2 Ntiles ----
    const short* w1base = (const short*)Wt1g + (w * 32 + lo) * WT1_LD + quad * 8;
    f32x4 acc1[4][2];
    #pragma unroll
    for (int mt = 0; mt < 4; ++mt) { acc1[mt][0] = (f32x4)0.f; acc1[mt][1] = (f32x4)0.f; }
    #pragma unroll
    for (int k = 0; k < 8; ++k) {
        bf16x8 bA = *(const bf16x8*)(w1base + k * 32);
        bf16x8 bB = *(const bf16x8*)(w1base + 16 * WT1_LD + k * 32);
        #pragma unroll
        for (int mt = 0; mt < 4; ++mt) {
            bf16x8 afr = *(const bf16x8*)&xs[mt * 16 + lo][k * 32 + quad * 8];
            acc1[mt][0] = __builtin_amdgcn_mfma_f32_16x16x32_bf16(afr, bA, acc1[mt][0], 0, 0, 0);
            acc1[mt][1] = __builtin_amdgcn_mfma_f32_16x16x32_bf16(afr, bB, acc1[mt][1], 0, 0, 0);
        }
    }
    // bias + exact GELU -> h1s (row = mt*16+quad*4+r, col = w*32+nt*16+lo)
    #pragma unroll
    for (int nt = 0; nt < 2; ++nt) {
        const float bb = b1[w * 32 + nt * 16 + lo];
        #pragma unroll
        for (int mt = 0; mt < 4; ++mt) {
            #pragma unroll
            for (int r = 0; r < 4; ++r) {
                float v = acc1[mt][nt][r] + bb;
                v = 0.5f * v * (1.0f + erff(v * 0.70710678118654752f));
                h1s[mt * 16 + quad * 4 + r][w * 32 + nt * 16 + lo] = __float2bfloat16(v);
            }
        }
    }
    __syncthreads();

    // ---- GEMM2: ang = h1[64,128] @ W2[128,64]; wave owns Mtile w, 4 Ntiles ----
    const short* w2base = (const short*)Wt2g + lo * WT2_LD + quad * 8;
    f32x4 acc2[4];
    #pragma unroll
    for (int nt = 0; nt < 4; ++nt) acc2[nt] = (f32x4)0.f;
    #pragma unroll
    for (int k = 0; k < 4; ++k) {
        bf16x8 afr = *(const bf16x8*)&h1s[w * 16 + lo][k * 32 + quad * 8];
        #pragma unroll
        for (int nt = 0; nt < 4; ++nt) {
            bf16x8 bfrg = *(const bf16x8*)(w2base + nt * 16 * WT2_LD + k * 32);
            acc2[nt] = __builtin_amdgcn_mfma_f32_16x16x32_bf16(afr, bfrg, acc2[nt], 0, 0, 0);
        }
    }
    __syncthreads();   // h1s reads done; csn may now overwrite the same LDS

    // tanh -> sincos -> interleaved csn (one 4B store per value pair)
    #pragma unroll
    for (int nt = 0; nt < 4; ++nt) {
        const float bb = b2[nt * 16 + lo];
        #pragma unroll
        for (int r = 0; r < 4; ++r) {
            float a = tanhf(acc2[nt][r] + bb);
            float sv, cv;
            sincosf(a, &sv, &cv);
            union { unsigned int u; __hip_bfloat16 h[2]; } p;
            p.h[0] = __float2bfloat16(cv);
            p.h[1] = __float2bfloat16(sv);
            *(unsigned int*)&csn[w * 16 + quad * 4 + r][2 * (nt * 16 + lo)] = p.u;
        }
    }
    __syncthreads();

    // ---- coalesced global write of interleaved cos/sin (8B per lane) ----
    #pragma unroll
    for (int m = 0; m < 8; ++m) {
        int idx = t + m * 256;            // 0..2047 : 64 rows x 32 qwords
        int row = idx >> 5;
        int d2 = (idx & 31);              // qword within row
        if (n0 + row < N_NODES) {
            uint2 v = *(const uint2*)&csn[row][d2 * 4];
            *(uint2*)(csng + (size_t)(n0 + row) * 128 + d2 * 4) = v;
        }
    }

    // ---- Phase D: rotate + segment-reduce pooled sums (thread = channel) ----
    {
        const int b = t >> 2;
        const int idx2 = t & 3;
        const int i2 = idx2 >> 1;
        const int f = idx2 & 1;
        float racc = 0.f, rcnt = 0.f;
        int gprev = gsh[0];
        #pragma unroll 8
        for (int r = 0; r < BLKN; ++r) {
            const int g = gsh[r];
            if (g != gprev) {
                atomicAdd(&gsums[gprev * GS + t], racc);
                if (t == 0) atomicAdd(&gsums[gprev * GS + 256], rcnt);
                racc = 0.f; rcnt = 0.f; gprev = g;
            }
            bf4 xq = *(const bf4*)&xs[r][4 * b];             // one ds_read_b64
            union { unsigned int u; __hip_bfloat16 h[2]; } cs;
            cs.u = *(const unsigned int*)&csn[r][2 * b];     // one ds_read_b32
            const float x0 = f ? bf2f(xq.y) : bf2f(xq.x);
            const float x1 = f ? bf2f(xq.w) : bf2f(xq.z);
            const float cb = bf2f(cs.h[0]);
            const float sb = bf2f(cs.h[1]);
            racc += (i2 == 0) ? (cb * x0 - sb * x1) : (sb * x0 + cb * x1);
            rcnt += (r < nrem) ? 1.f : 0.f;
        }
        atomicAdd(&gsums[gprev * GS + t], racc);
        if (t == 0) atomicAdd(&gsums[gprev * GS + 256], rcnt);
    }
}

// ---------------------------------------------------------------------------
// K2: hmean[g] = (gsum[g] @ lin_w) / cnt + lin_b   (0 if cnt == 0)
// ---------------------------------------------------------------------------
__global__ __launch_bounds__(256)
void k2_hmean(const float* __restrict__ gsums, const float* __restrict__ lin_w,
              const float* __restrict__ lin_b, float* __restrict__ hmean)
{
    __shared__ float gs[C];
    __shared__ float cnt_sh;
    const int g = blockIdx.x;
    const int t = threadIdx.x;
    gs[t] = gsums[g * GS + t];
    if (t == 0) cnt_sh = gsums[g * GS + 256];
    __syncthreads();
    float a0 = 0.f, a1 = 0.f, a2 = 0.f, a3 = 0.f;
    #pragma unroll 4
    for (int k = 0; k < C; k += 4) {
        a0 += gs[k + 0] * lin_w[(size_t)(k + 0) * C + t];
        a1 += gs[k + 1] * lin_w[(size_t)(k + 1) * C + t];
        a2 += gs[k + 2] * lin_w[(size_t)(k + 2) * C + t];
        a3 += gs[k + 3] * lin_w[(size_t)(k + 3) * C + t];
    }
    const float cnt = cnt_sh;
    hmean[g * C + t] = (cnt > 0.f) ? ((a0 + a1 + a2 + a3) / cnt + lin_b[t]) : 0.f;
}

// ---------------------------------------------------------------------------
// K3: BN statistics only (no out store): o = x + R^T hmean[batch[n]] on the fly.
// ---------------------------------------------------------------------------
__global__ __launch_bounds__(256, 4)
void k3_stats(const float* __restrict__ x,
              const int* __restrict__ batch,
              const __hip_bfloat16* __restrict__ csng,
              const float* __restrict__ hmean,
              float* __restrict__ bnsum, float* __restrict__ bnsq)
{
    __shared__ float rs[4][C];
    __shared__ float rq[4][C];
    const int t = threadIdx.x;
    const int s = t >> 6;
    const int cg = t & 63;
    float bs0 = 0.f, bs1 = 0.f, bs2 = 0.f, bs3 = 0.f;
    float bq0 = 0.f, bq1 = 0.f, bq2 = 0.f, bq3 = 0.f;

    for (int base = blockIdx.x * 4; base < N_NODES; base += gridDim.x * 4) {
        const int n = base + s;
        if (n < N_NODES) {
            const int g = batch[n];
            const float4 hm = *(const float4*)(hmean + (size_t)g * C + cg * 4);
            union { unsigned int u; __hip_bfloat16 h[2]; } cs;
            cs.u = *(const unsigned int*)(csng + (size_t)n * 128 + cg * 2);
            const float cv = bf2f(cs.h[0]);
            const float sv = bf2f(cs.h[1]);
            const float4 xv = *(const float4*)(x + (size_t)n * C + cg * 4);
            float4 o;
            o.x = xv.x + cv * hm.x + sv * hm.z;
            o.y = xv.y + cv * hm.y + sv * hm.w;
            o.z = xv.z - sv * hm.x + cv * hm.z;
            o.w = xv.w - sv * hm.y + cv * hm.w;
            bs0 += o.x; bs1 += o.y; bs2 += o.z; bs3 += o.w;
            bq0 += o.x * o.x; bq1 += o.y * o.y; bq2 += o.z * o.z; bq3 += o.w * o.w;
        }
    }
    rs[s][cg * 4 + 0] = bs0; rs[s][cg * 4 + 1] = bs1;
    rs[s][cg * 4 + 2] = bs2; rs[s][cg * 4 + 3] = bs3;
    rq[s][cg * 4 + 0] = bq0; rq[s][cg * 4 + 1] = bq1;
    rq[s][cg * 4 + 2] = bq2; rq[s][cg * 4 + 3] = bq3;
    __syncthreads();
    atomicAdd(&bnsum[t], rs[0][t] + rs[1][t] + rs[2][t] + rs[3][t]);
    atomicAdd(&bnsq[t],  rq[0][t] + rq[1][t] + rq[2][t] + rq[3][t]);
}

// ---------------------------------------------------------------------------
// K4: recompute o = x + R^T hmean and write normalized output (single pass).
// ---------------------------------------------------------------------------
__global__ __launch_bounds__(256, 4)
void k4_fused(const float* __restrict__ x,
              const int* __restrict__ batch,
              const __hip_bfloat16* __restrict__ csng,
              const float* __restrict__ hmean,
              const float* __restrict__ bnsum, const float* __restrict__ bnsq,
              const float* __restrict__ gamma, const float* __restrict__ beta,
              float* __restrict__ out)
{
    __shared__ float mul_s[C], add_s[C];
    const int t = threadIdx.x;
    {
        const float inv_n = 1.0f / (float)N_NODES;
        const float mu = bnsum[t] * inv_n;
        const float var = bnsq[t] * inv_n - mu * mu;
        const float inv = rsqrtf(var + BN_EPS);
        const float m = gamma[t] * inv;
        mul_s[t] = m;
        add_s[t] = beta[t] - mu * m;
    }
    __syncthreads();
    const int s = t >> 6;
    const int cg = t & 63;
    const float4 mm = *(const float4*)&mul_s[cg * 4];
    const float4 aa = *(const float4*)&add_s[cg * 4];

    for (int base = blockIdx.x * 4; base < N_NODES; base += gridDim.x * 4) {
        const int n = base + s;
        if (n < N_NODES) {
            const int g = batch[n];
            const float4 hm = *(const float4*)(hmean + (size_t)g * C + cg * 4);
            union { unsigned int u; __hip_bfloat16 h[2]; } cs;
            cs.u = *(const unsigned int*)(csng + (size_t)n * 128 + cg * 2);
            const float cv = bf2f(cs.h[0]);
            const float sv = bf2f(cs.h[1]);
            const float4 xv = *(const float4*)(x + (size_t)n * C + cg * 4);
            float4 o;
            o.x = (xv.x + cv * hm.x + sv * hm.z) * mm.x + aa.x;
            o.y = (xv.y + cv * hm.y + sv * hm.w) * mm.y + aa.y;
            o.z = (xv.z - sv * hm.x + cv * hm.z) * mm.z + aa.z;
            o.w = (xv.w - sv * hm.y + cv * hm.w) * mm.w + aa.w;
            *(float4*)(out + (size_t)n * C + cg * 4) = o;
        }
    }
}

// ---------------------------------------------------------------------------
extern "C" void kernel_launch(void* const* d_in, const int* in_sizes, int n_in,
                              void* d_out, int out_size, void* d_ws, size_t ws_size,
                              hipStream_t stream)
{
    const float* x      = (const float*)d_in[0];
    // d_in[1] = edge_index (unused, num_gnn == 0)
    const int* batch    = (const int*)d_in[2];
    const float* W1     = (const float*)d_in[3];
    const float* b1     = (const float*)d_in[4];
    const float* W2     = (const float*)d_in[5];
    const float* b2     = (const float*)d_in[6];
    const float* lin_w  = (const float*)d_in[7];
    const float* lin_b  = (const float*)d_in[8];
    const float* gamma  = (const float*)d_in[9];
    const float* beta   = (const float*)d_in[10];

    float* ws    = (float*)d_ws;
    float* gsums = ws + OFF_GSUMS;
    float* bnsum = ws + OFF_BNSUM;
    float* bnsq  = ws + OFF_BNSQ;
    float* hmean = ws + OFF_HMEAN;
    __hip_bfloat16* Wt1  = (__hip_bfloat16*)(ws + OFF_WT1);
    __hip_bfloat16* Wt2  = (__hip_bfloat16*)(ws + OFF_WT2);
    __hip_bfloat16* csng = (__hip_bfloat16*)(ws + OFF_CSN);
    float* out   = (float*)d_out;

    hipMemsetAsync(gsums, 0, ZERO_FLOATS * sizeof(float), stream);

    k0_prep<<<32, 256, 0, stream>>>(W1, W2, Wt1, Wt2);
    k1_angles_rot_pool<<<NBLK1, 256, 0, stream>>>(x, batch, Wt1, b1, Wt2, b2,
                                                  gsums, csng);
    k2_hmean<<<NG, 256, 0, stream>>>(gsums, lin_w, lin_b, hmean);
    k3_stats<<<1024, 256, 0, stream>>>(x, batch, csng, hmean, bnsum, bnsq);
    k4_fused<<<2048, 256, 0, stream>>>(x, batch, csng, hmean, bnsum, bnsq,
                                       gamma, beta, out);
}

// Round 6
// 319.079 us; speedup vs baseline: 1.2373x; 1.0871x over previous
//
#include <hip/hip_runtime.h>
#include <hip/hip_bf16.h>
#include <math.h>

#define N_NODES 100000
#define C 256
#define NB 64
#define H1D 128
#define NG 128
#define BN_EPS 1e-5f

#define BLKN 32
#define NBLK1 (N_NODES / BLKN)           // 3125 exactly, no tail

// per-graph record: XC[256] | XS[256] | BS[256] (b*4+{CV,SV,CC,CS}) | cnt
#define GREC 769

// ws layout (float offsets)
#define OFF_GSUMS 0
#define OFF_BNSUM (NG * GREC)            // 98432
#define OFF_BNSQ  (OFF_BNSUM + 256)      // 98688
#define ZERO_FLOATS (OFF_BNSQ + 256)     // 98944 floats zeroed each launch
#define OFF_HMEAN ZERO_FLOATS            // 98944
#define OFF_WT1   (OFF_HMEAN + NG * C)   // +32768
#define OFF_WT2   (OFF_WT1 + 16896)
#define OFF_CSN   (OFF_WT2 + 4352)       // N*128 bf16 = 6.4M floats

#define WT1_LD 264   // bf16 stride of Wt1 in global (16B-aligned rows)
#define WT2_LD 136
#define XS_LD  272   // bf16 LDS stride: row shift = 8 banks -> 4-way max on b128

typedef __attribute__((ext_vector_type(8))) short bf16x8;
typedef __attribute__((ext_vector_type(4))) float f32x4;

struct __align__(8) bf4 { __hip_bfloat16 x, y, z, w; };

__device__ __forceinline__ float bf2f(__hip_bfloat16 h) { return __bfloat162float(h); }

__device__ __forceinline__ float fast_tanh(float y) {
    // exact identity, fast exp (v_exp); y bounded (~|y|<6) in this net
    float e = __expf(2.f * y);
    return 1.f - 2.f / (e + 1.f);
}
__device__ __forceinline__ float fast_gelu(float v) {
    // tanh-form GELU, max abs err ~1.5e-3 vs exact-erf (threshold 0.11)
    float u = 0.7978845608f * (v + 0.044715f * v * v * v);
    return 0.5f * v * (1.f + fast_tanh(u));
}

// ---------------------------------------------------------------------------
// K0: transpose+convert weights to bf16 [out_ch][in_ch] layout for MFMA B-frags
// ---------------------------------------------------------------------------
__global__ __launch_bounds__(256)
void k0_prep(const float* __restrict__ W1, const float* __restrict__ W2,
             __hip_bfloat16* __restrict__ Wt1, __hip_bfloat16* __restrict__ Wt2)
{
    const int t0 = threadIdx.x + blockIdx.x * 256;
    const int stride = gridDim.x * 256;
    for (int i = t0; i < 128 * 256; i += stride) {
        int n = i >> 8, k = i & 255;
        Wt1[n * WT1_LD + k] = __float2bfloat16(W1[k * 128 + n]);
    }
    for (int i = t0; i < 64 * 128; i += stride) {
        int n = i >> 7, k = i & 127;
        Wt2[n * WT2_LD + k] = __float2bfloat16(W2[k * 64 + n]);
    }
}

// ---------------------------------------------------------------------------
// K1: 32-node tile. MFMA GEMM1 -> fast GELU -> MFMA GEMM2 -> fast tanh/sincos;
//     write interleaved cos/sin (bf16); accumulate per-graph stats:
//     XC[c]=sum x*cv, XS[c]=sum x*sv, BS[4b+{0..3}]={sum cv,sv,cv^2,cv*sv}, cnt;
//     plus global per-channel sum x, sum x^2 into bnsum/bnsq.
// ---------------------------------------------------------------------------
__global__ __launch_bounds__(256, 6)
void k1_angles_rot_pool(const float* __restrict__ x,
                        const int* __restrict__ batch,
                        const __hip_bfloat16* __restrict__ Wt1g,
                        const float* __restrict__ b1,
                        const __hip_bfloat16* __restrict__ Wt2g,
                        const float* __restrict__ b2,
                        float* __restrict__ gsums,
                        float* __restrict__ bnsum, float* __restrict__ bnsq,
                        __hip_bfloat16* __restrict__ csng)
{
    __shared__ __hip_bfloat16 xs[BLKN][XS_LD];  // 17408 B
    __shared__ char sm_u[BLKN * WT2_LD * 2];    // 8704 B: h1s, later csn (aliased)
    __shared__ int gsh[BLKN];                   // 128 B  -> 26240 B total, 6 blk/CU
    auto h1s = (__hip_bfloat16 (*)[WT2_LD])sm_u;   // stride 136
    auto csn = (__hip_bfloat16 (*)[132])sm_u;      // stride 132: [2c]=cos,[2c+1]=sin

    const int t = threadIdx.x;
    const int w = t >> 6;                 // wave 0..3
    const int l = t & 63;
    const int lo = l & 15, quad = l >> 4;
    const int n0 = blockIdx.x * BLKN;

    // ---- Phase A: x fp32 -> bf16 LDS tile; batch tile ----
    #pragma unroll
    for (int m = 0; m < 8; ++m) {
        int idx = t + m * 256;            // 0..2047 float4: 32 rows x 64
        int r = idx >> 6, c4 = (idx & 63) * 4;
        float4 v = *(const float4*)(x + (size_t)(n0 + r) * C + c4);
        bf4 pk;
        pk.x = __float2bfloat16(v.x); pk.y = __float2bfloat16(v.y);
        pk.z = __float2bfloat16(v.z); pk.w = __float2bfloat16(v.w);
        *(bf4*)&xs[r][c4] = pk;
    }
    if (t < BLKN) gsh[t] = batch[n0 + t];
    __syncthreads();

    // ---- GEMM1: h1 = x[32,256] @ W1[256,128]; wave: 2 Mtiles x 2 Ntiles ----
    const short* w1base = (const short*)Wt1g + (w * 32 + lo) * WT1_LD + quad * 8;
    f32x4 acc1[2][2];
    #pragma unroll
    for (int mt = 0; mt < 2; ++mt) { acc1[mt][0] = (f32x4)0.f; acc1[mt][1] = (f32x4)0.f; }
    #pragma unroll
    for (int k = 0; k < 8; ++k) {
        bf16x8 bA = *(const bf16x8*)(w1base + k * 32);
        bf16x8 bB = *(const bf16x8*)(w1base + 16 * WT1_LD + k * 32);
        #pragma unroll
        for (int mt = 0; mt < 2; ++mt) {
            bf16x8 afr = *(const bf16x8*)&xs[mt * 16 + lo][k * 32 + quad * 8];
            acc1[mt][0] = __builtin_amdgcn_mfma_f32_16x16x32_bf16(afr, bA, acc1[mt][0], 0, 0, 0);
            acc1[mt][1] = __builtin_amdgcn_mfma_f32_16x16x32_bf16(afr, bB, acc1[mt][1], 0, 0, 0);
        }
    }
    // bias + fast GELU -> h1s (row = mt*16+quad*4+r, col = w*32+nt*16+lo)
    #pragma unroll
    for (int nt = 0; nt < 2; ++nt) {
        const float bb = b1[w * 32 + nt * 16 + lo];
        #pragma unroll
        for (int mt = 0; mt < 2; ++mt) {
            #pragma unroll
            for (int r = 0; r < 4; ++r) {
                float v = fast_gelu(acc1[mt][nt][r] + bb);
                h1s[mt * 16 + quad * 4 + r][w * 32 + nt * 16 + lo] = __float2bfloat16(v);
            }
        }
    }
    __syncthreads();

    // ---- GEMM2: ang = h1[32,128] @ W2[128,64]; wave (w>>1)=Mtile, (w&1)=Npair ----
    const int mw = w >> 1;
    const int nb0 = (w & 1) * 32;
    const short* w2base = (const short*)Wt2g + (nb0 + lo) * WT2_LD + quad * 8;
    f32x4 acc2[2];
    acc2[0] = (f32x4)0.f; acc2[1] = (f32x4)0.f;
    #pragma unroll
    for (int k = 0; k < 4; ++k) {
        bf16x8 afr = *(const bf16x8*)&h1s[mw * 16 + lo][k * 32 + quad * 8];
        bf16x8 bA = *(const bf16x8*)(w2base + k * 32);
        bf16x8 bB = *(const bf16x8*)(w2base + 16 * WT2_LD + k * 32);
        acc2[0] = __builtin_amdgcn_mfma_f32_16x16x32_bf16(afr, bA, acc2[0], 0, 0, 0);
        acc2[1] = __builtin_amdgcn_mfma_f32_16x16x32_bf16(afr, bB, acc2[1], 0, 0, 0);
    }
    __syncthreads();   // h1s reads done; csn may now overwrite the same LDS

    // fast tanh -> hw sincos -> interleaved csn
    #pragma unroll
    for (int nt = 0; nt < 2; ++nt) {
        const int col = nb0 + nt * 16 + lo;
        const float bb = b2[col];
        #pragma unroll
        for (int r = 0; r < 4; ++r) {
            float a = fast_tanh(acc2[nt][r] + bb);
            union { unsigned int u; __hip_bfloat16 h[2]; } p;
            p.h[0] = __float2bfloat16(__cosf(a));
            p.h[1] = __float2bfloat16(__sinf(a));
            *(unsigned int*)&csn[mw * 16 + quad * 4 + r][2 * col] = p.u;
        }
    }
    __syncthreads();

    // ---- coalesced global write of interleaved cos/sin (8B per lane) ----
    #pragma unroll
    for (int m = 0; m < 4; ++m) {
        int idx = t + m * 256;            // 0..1023 : 32 rows x 32 qwords
        int row = idx >> 5;
        int q = (idx & 31);
        uint2 v = *(const uint2*)&csn[row][q * 4];
        *(uint2*)(csng + (size_t)(n0 + row) * 128 + q * 4) = v;
    }

    // ---- Phase D: per-graph stat accumulation (thread = channel) ----
    {
        const int c = t;
        const int b = c >> 2;
        const int idx2 = c & 3;          // BS index = 4b+idx2 = t
        float xc_a = 0.f, xs_a = 0.f, xm = 0.f, xq = 0.f, st = 0.f, rcnt = 0.f;
        int gprev = gsh[0];
        #pragma unroll 8
        for (int r = 0; r < BLKN; ++r) {
            const int g = gsh[r];
            if (g != gprev) {
                float* rec = gsums + (size_t)gprev * GREC;
                atomicAdd(&rec[c], xc_a);
                atomicAdd(&rec[256 + c], xs_a);
                atomicAdd(&rec[512 + t], st);
                if (t == 0) atomicAdd(&rec[768], rcnt);
                xc_a = 0.f; xs_a = 0.f; st = 0.f; rcnt = 0.f; gprev = g;
            }
            const float xv = bf2f(xs[r][c]);
            union { unsigned int u; __hip_bfloat16 h[2]; } cs;
            cs.u = *(const unsigned int*)&csn[r][2 * b];
            const float cv = bf2f(cs.h[0]);
            const float sv = bf2f(cs.h[1]);
            xc_a += xv * cv;
            xs_a += xv * sv;
            xm += xv;
            xq += xv * xv;
            st += (idx2 == 0) ? cv : (idx2 == 1) ? sv : (idx2 == 2) ? cv * cv : cv * sv;
            rcnt += 1.f;
        }
        float* rec = gsums + (size_t)gprev * GREC;
        atomicAdd(&rec[c], xc_a);
        atomicAdd(&rec[256 + c], xs_a);
        atomicAdd(&rec[512 + t], st);
        if (t == 0) atomicAdd(&rec[768], rcnt);
        atomicAdd(&bnsum[c], xm);
        atomicAdd(&bnsq[c], xq);
    }
}

// ---------------------------------------------------------------------------
// K2: per graph: reconstruct rotated pool sums, hmean = (grot @ lin_w)/cnt + b;
//     add closed-form BN contributions of o = x + R^T hmean to bnsum/bnsq.
// ---------------------------------------------------------------------------
__global__ __launch_bounds__(256)
void k2_hmean_stats(const float* __restrict__ gsums,
                    const float* __restrict__ lin_w, const float* __restrict__ lin_b,
                    float* __restrict__ hmean,
                    float* __restrict__ bnsum, float* __restrict__ bnsq)
{
    __shared__ float xc[C], xsv[C], bs4[C], grot[C], hm[C];
    __shared__ float cnt_sh;
    const int g = blockIdx.x;
    const int t = threadIdx.x;
    const float* rec = gsums + (size_t)g * GREC;
    xc[t]  = rec[t];
    xsv[t] = rec[256 + t];
    bs4[t] = rec[512 + t];
    if (t == 0) cnt_sh = rec[768];
    __syncthreads();

    const int b = t >> 2, idx2 = t & 3, i2 = idx2 >> 1;
    // rotated pool sum: c0=4b+f pairs with c1=4b+2+f
    grot[t] = (i2 == 0) ? (xc[t] - xsv[t + 2]) : (xsv[t - 2] + xc[t]);
    __syncthreads();

    float a0 = 0.f, a1 = 0.f, a2 = 0.f, a3 = 0.f;
    #pragma unroll 4
    for (int k = 0; k < C; k += 4) {
        a0 += grot[k + 0] * lin_w[(size_t)(k + 0) * C + t];
        a1 += grot[k + 1] * lin_w[(size_t)(k + 1) * C + t];
        a2 += grot[k + 2] * lin_w[(size_t)(k + 2) * C + t];
        a3 += grot[k + 3] * lin_w[(size_t)(k + 3) * C + t];
    }
    const float cnt = cnt_sh;
    const float hv = (cnt > 0.f) ? ((a0 + a1 + a2 + a3) / cnt + lin_b[t]) : 0.f;
    hm[t] = hv;
    hmean[g * C + t] = hv;
    __syncthreads();

    if (cnt > 0.f) {
        const int f = idx2 & 1;
        const float h0 = hm[4 * b + f];
        const float h1 = hm[4 * b + 2 + f];
        const float CV = bs4[4 * b + 0], SV = bs4[4 * b + 1];
        const float CC = bs4[4 * b + 2], CS = bs4[4 * b + 3];
        const float SS = cnt - CC;       // cv^2+sv^2 = 1 (bf16 eps negligible here)
        float sumc, sqc;
        if (i2 == 0) {
            sumc = h0 * CV + h1 * SV;
            sqc  = 2.f * (h0 * xc[t] + h1 * xsv[t])
                 + h0 * h0 * CC + 2.f * h0 * h1 * CS + h1 * h1 * SS;
        } else {
            sumc = -h0 * SV + h1 * CV;
            sqc  = 2.f * (-h0 * xsv[t] + h1 * xc[t])
                 + h0 * h0 * SS - 2.f * h0 * h1 * CS + h1 * h1 * CC;
        }
        atomicAdd(&bnsum[t], sumc);
        atomicAdd(&bnsq[t], sqc);
    }
}

// ---------------------------------------------------------------------------
// K4: o = x + R^T hmean[batch[n]], normalized, single output pass.
// ---------------------------------------------------------------------------
__global__ __launch_bounds__(256, 4)
void k4_fused(const float* __restrict__ x,
              const int* __restrict__ batch,
              const __hip_bfloat16* __restrict__ csng,
              const float* __restrict__ hmean,
              const float* __restrict__ bnsum, const float* __restrict__ bnsq,
              const float* __restrict__ gamma, const float* __restrict__ beta,
              float* __restrict__ out)
{
    __shared__ float mul_s[C], add_s[C];
    const int t = threadIdx.x;
    {
        const float inv_n = 1.0f / (float)N_NODES;
        const float mu = bnsum[t] * inv_n;
        const float var = bnsq[t] * inv_n - mu * mu;
        const float inv = rsqrtf(var + BN_EPS);
        const float m = gamma[t] * inv;
        mul_s[t] = m;
        add_s[t] = beta[t] - mu * m;
    }
    __syncthreads();
    const int s = t >> 6;
    const int cg = t & 63;
    const float4 mm = *(const float4*)&mul_s[cg * 4];
    const float4 aa = *(const float4*)&add_s[cg * 4];

    for (int base = blockIdx.x * 4; base < N_NODES; base += gridDim.x * 4) {
        const int n = base + s;
        if (n < N_NODES) {
            const int g = batch[n];
            const float4 hm = *(const float4*)(hmean + (size_t)g * C + cg * 4);
            union { unsigned int u; __hip_bfloat16 h[2]; } cs;
            cs.u = *(const unsigned int*)(csng + (size_t)n * 128 + cg * 2);
            const float cv = bf2f(cs.h[0]);
            const float sv = bf2f(cs.h[1]);
            const float4 xv = *(const float4*)(x + (size_t)n * C + cg * 4);
            float4 o;
            o.x = (xv.x + cv * hm.x + sv * hm.z) * mm.x + aa.x;
            o.y = (xv.y + cv * hm.y + sv * hm.w) * mm.y + aa.y;
            o.z = (xv.z - sv * hm.x + cv * hm.z) * mm.z + aa.z;
            o.w = (xv.w - sv * hm.y + cv * hm.w) * mm.w + aa.w;
            *(float4*)(out + (size_t)n * C + cg * 4) = o;
        }
    }
}

// ---------------------------------------------------------------------------
extern "C" void kernel_launch(void* const* d_in, const int* in_sizes, int n_in,
                              void* d_out, int out_size, void* d_ws, size_t ws_size,
                              hipStream_t stream)
{
    const float* x      = (const float*)d_in[0];
    // d_in[1] = edge_index (unused, num_gnn == 0)
    const int* batch    = (const int*)d_in[2];
    const float* W1     = (const float*)d_in[3];
    const float* b1     = (const float*)d_in[4];
    const float* W2     = (const float*)d_in[5];
    const float* b2     = (const float*)d_in[6];
    const float* lin_w  = (const float*)d_in[7];
    const float* lin_b  = (const float*)d_in[8];
    const float* gamma  = (const float*)d_in[9];
    const float* beta   = (const float*)d_in[10];

    float* ws    = (float*)d_ws;
    float* gsums = ws + OFF_GSUMS;
    float* bnsum = ws + OFF_BNSUM;
    float* bnsq  = ws + OFF_BNSQ;
    float* hmean = ws + OFF_HMEAN;
    __hip_bfloat16* Wt1  = (__hip_bfloat16*)(ws + OFF_WT1);
    __hip_bfloat16* Wt2  = (__hip_bfloat16*)(ws + OFF_WT2);
    __hip_bfloat16* csng = (__hip_bfloat16*)(ws + OFF_CSN);
    float* out   = (float*)d_out;

    hipMemsetAsync(gsums, 0, ZERO_FLOATS * sizeof(float), stream);

    k0_prep<<<32, 256, 0, stream>>>(W1, W2, Wt1, Wt2);
    k1_angles_rot_pool<<<NBLK1, 256, 0, stream>>>(x, batch, Wt1, b1, Wt2, b2,
                                                  gsums, bnsum, bnsq, csng);
    k2_hmean_stats<<<NG, 256, 0, stream>>>(gsums, lin_w, lin_b, hmean, bnsum, bnsq);
    k4_fused<<<2048, 256, 0, stream>>>(x, batch, csng, hmean, bnsum, bnsq,
                                       gamma, beta, out);
}